// Round 1
// baseline (60.082 us; speedup 1.0000x reference)
//
#include <hip/hip_runtime.h>
#include <math.h>

#define DIM 64
#define NE 4
#define B_SZ 4
#define NQ 4096
#define NK 4096
#define BQ 8      // q-rows per writer block
#define KT 1024   // k-cols per writer block

// ---------------------------------------------------------------------------
// Kernel 1: per-row features. One 64-lane wave per row.
// Features (5 per row):
//   qf[e=0] = amp * exp(-0.5*surf(q)^2)        kf[e=0] = exp(-0.5*surf(k)^2)
//   qf[e>0] = amp * exp(-0.5*||q-p_e||^2)      kf[e>0] = w_e * exp(-0.5*||k-p_e||^2)
// Layout: feat-major  f[b][e][row]  so the writer's loads are coalesced.
// ---------------------------------------------------------------------------
__global__ __launch_bounds__(256) void feat_kernel(
    const float* __restrict__ queries,
    const float* __restrict__ keys,
    const float* __restrict__ center,
    const float* __restrict__ outer_radius,
    const float* __restrict__ hole_radius,
    const float* __restrict__ entry_points,
    const float* __restrict__ entry_strengths,
    const float* __restrict__ amplitude,
    float* __restrict__ qf,   // [B][5][NQ]
    float* __restrict__ kf)   // [B][5][NK]
{
    const int wave = (blockIdx.x * blockDim.x + threadIdx.x) >> 6;
    const int lane = threadIdx.x & 63;
    const int nqrows = B_SZ * NQ;
    const int total  = nqrows + B_SZ * NK;
    if (wave >= total) return;

    const bool is_q = wave < nqrows;
    const int  row  = is_q ? wave : (wave - nqrows);
    const float* src = is_q ? (queries + (size_t)row * DIM)
                            : (keys    + (size_t)row * DIM);

    const float x = src[lane];

    float d0 = x - center[lane];
    float d1 = x - entry_points[0 * DIM + lane];
    float d2 = x - entry_points[1 * DIM + lane];
    float d3 = x - entry_points[2 * DIM + lane];
    float d4 = x - entry_points[3 * DIM + lane];
    float a0 = d0 * d0;
    float a1 = d1 * d1;
    float a2 = d2 * d2;
    float a3 = d3 * d3;
    float a4 = d4 * d4;

    #pragma unroll
    for (int off = 32; off >= 1; off >>= 1) {
        a0 += __shfl_xor(a0, off, 64);
        a1 += __shfl_xor(a1, off, 64);
        a2 += __shfl_xor(a2, off, 64);
        a3 += __shfl_xor(a3, off, 64);
        a4 += __shfl_xor(a4, off, 64);
    }

    if (lane == 0) {
        const float outer_r    = fabsf(outer_radius[0]) + 1e-8f;
        const float hole_r     = fabsf(hole_radius[0]);
        const float hole_ratio = hole_r / outer_r;
        const float amp        = amplitude[0];

        const float dist  = sqrtf(a0);
        const float major = fabsf(dist - outer_r);
        const float torus = fabsf(sqrtf(major * major + hole_r * hole_r) - hole_r);
        const float surf  = (hole_ratio < 0.1f) ? major : torus;

        const float f0 = expf(-0.5f * surf * surf);
        const float f1 = expf(-0.5f * a1);
        const float f2 = expf(-0.5f * a2);
        const float f3 = expf(-0.5f * a3);
        const float f4 = expf(-0.5f * a4);

        const int b = row / (is_q ? NQ : NK);
        const int r = row - b * (is_q ? NQ : NK);

        if (is_q) {
            float* dst = qf + ((size_t)b * 5) * NQ + r;
            dst[0 * NQ] = amp * f0;
            dst[1 * NQ] = amp * f1;
            dst[2 * NQ] = amp * f2;
            dst[3 * NQ] = amp * f3;
            dst[4 * NQ] = amp * f4;
        } else {
            // entry weights: sigmoid(strength), masked at > 0.1
            float w[NE];
            #pragma unroll
            for (int e = 0; e < NE; ++e) {
                float s = 1.0f / (1.0f + expf(-entry_strengths[e]));
                w[e] = (s > 0.1f) ? s : 0.0f;
            }
            float* dst = kf + ((size_t)b * 5) * NK + r;
            dst[0 * NK] = f0;
            dst[1 * NK] = w[0] * f1;
            dst[2 * NK] = w[1] * f2;
            dst[3 * NK] = w[2] * f3;
            dst[4 * NK] = w[3] * f4;
        }
    }
}

// ---------------------------------------------------------------------------
// Kernel 2: streaming writer. out[b,q,k] = dot5(qf[b,:,q], kf[b,:,k]).
// Block = 256 threads handles BQ=8 rows x KT=1024 cols.
// Each thread: 5 float4 k-feature loads (L2-hit after first row-group),
// 40 uniform q-feature loads (scalar), 8 coalesced float4 stores.
// ---------------------------------------------------------------------------
__global__ __launch_bounds__(256) void write_kernel(
    const float* __restrict__ qf,
    const float* __restrict__ kf,
    float* __restrict__ out)
{
    const int b  = blockIdx.z;
    const int q0 = blockIdx.y * BQ;
    const int k0 = blockIdx.x * KT + threadIdx.x * 4;

    const float* qfb = qf + ((size_t)b * 5) * NQ + q0;
    const float* kfb = kf + ((size_t)b * 5) * NK + k0;

    float4 kc[5];
    #pragma unroll
    for (int e = 0; e < 5; ++e)
        kc[e] = *reinterpret_cast<const float4*>(kfb + (size_t)e * NK);

    float qv[5][BQ];
    #pragma unroll
    for (int e = 0; e < 5; ++e)
        #pragma unroll
        for (int r = 0; r < BQ; ++r)
            qv[e][r] = qfb[(size_t)e * NQ + r];

    float* orow = out + ((size_t)(b * NQ + q0)) * NK + k0;

    #pragma unroll
    for (int r = 0; r < BQ; ++r) {
        float4 v;
        v.x = qv[0][r] * kc[0].x + qv[1][r] * kc[1].x + qv[2][r] * kc[2].x
            + qv[3][r] * kc[3].x + qv[4][r] * kc[4].x;
        v.y = qv[0][r] * kc[0].y + qv[1][r] * kc[1].y + qv[2][r] * kc[2].y
            + qv[3][r] * kc[3].y + qv[4][r] * kc[4].y;
        v.z = qv[0][r] * kc[0].z + qv[1][r] * kc[1].z + qv[2][r] * kc[2].z
            + qv[3][r] * kc[3].z + qv[4][r] * kc[4].z;
        v.w = qv[0][r] * kc[0].w + qv[1][r] * kc[1].w + qv[2][r] * kc[2].w
            + qv[3][r] * kc[3].w + qv[4][r] * kc[4].w;
        *reinterpret_cast<float4*>(orow + (size_t)r * NK) = v;
    }
}

extern "C" void kernel_launch(void* const* d_in, const int* in_sizes, int n_in,
                              void* d_out, int out_size, void* d_ws, size_t ws_size,
                              hipStream_t stream) {
    const float* queries         = (const float*)d_in[0];
    const float* keys            = (const float*)d_in[1];
    const float* center          = (const float*)d_in[2];
    const float* outer_radius    = (const float*)d_in[3];
    const float* hole_radius     = (const float*)d_in[4];
    const float* entry_points    = (const float*)d_in[5];
    const float* entry_strengths = (const float*)d_in[6];
    const float* amplitude       = (const float*)d_in[7];

    float* qf = (float*)d_ws;                              // B*5*NQ floats
    float* kf = qf + (size_t)B_SZ * 5 * NQ;                // B*5*NK floats
    float* out = (float*)d_out;

    // Kernel 1: 32768 rows, 4 waves/block -> 8192 blocks
    {
        const int total_rows = B_SZ * NQ + B_SZ * NK;
        const int waves_per_block = 4;
        const int blocks = (total_rows + waves_per_block - 1) / waves_per_block;
        feat_kernel<<<blocks, 256, 0, stream>>>(
            queries, keys, center, outer_radius, hole_radius,
            entry_points, entry_strengths, amplitude, qf, kf);
    }

    // Kernel 2: (NK/KT, NQ/BQ, B) = (4, 512, 4) blocks of 256
    {
        dim3 grid(NK / KT, NQ / BQ, B_SZ);
        write_kernel<<<grid, 256, 0, stream>>>(qf, kf, out);
    }
}